// Round 7
// baseline (1012.247 us; speedup 1.0000x reference)
//
#include <hip/hip_runtime.h>
#include <cfloat>

// VQ forward, MI355X. z[16,256,32,32] f32, emb[8192,256] f32, proj[256,256] f32.
// N = 16384 rows, K = 8192 codes, D = 256.
// d_out (floats): out[4194304] | loss | commitment | codebook_loss | idx_as_float[16384]
//
// R7 two-phase argmin (R6 post-mortem: single-pass MFMA scores carry ~4e-7 error ->
// ~12 near-cell-boundary index flips vs the fp32-chain scores that passed R2-R5):
//   pass1: split-bf16 MFMA computes approx scores, keeps block-shared per-row running
//          min, appends candidates within DLT of it (DLT = 25x the error bound ->
//          the exact winner is always captured; ~11 survivors/row).
//   rescore: per survivor, BIT-IDENTICAL ascending-d fp32 fmaf chain as R2-R5 +
//          quantized fold fl(fl(znorm+nk)-2*acc) + packed (monof<<32|k) atomicMin
//          -> final output bit-identical to R5 (which passed, absmax 1.9e-6).

constexpr int Dd = 256;
constexpr int Kc = 8192;
constexpr float INV_M = 1.0f / 4194304.0f;
constexpr unsigned CAP = 2u * 1024u * 1024u;   // survivor list capacity
constexpr float DLT = 3.05e-5f;                // filter margin (need only ~1.2e-6)

typedef unsigned short u16;
typedef __attribute__((ext_vector_type(8))) short short8;   // 8 bf16 (4 VGPRs)
typedef __attribute__((ext_vector_type(4))) float f32x4;

__device__ __forceinline__ unsigned monof(float f) {
  unsigned u = __float_as_uint(f);
  return (u & 0x80000000u) ? ~u : (u | 0x80000000u);
}
__device__ __forceinline__ float unmonof(unsigned p) {
  unsigned u = (p & 0x80000000u) ? (p & 0x7FFFFFFFu) : ~p;
  return __uint_as_float(u);
}
__device__ __forceinline__ u16 f2bf(float x) {          // RNE float->bf16 bits
  unsigned u = __float_as_uint(x);
  u += 0x7FFFu + ((u >> 16) & 1u);
  return (u16)(u >> 16);
}
__device__ __forceinline__ float bf2f(u16 b) {
  return __uint_as_float(((unsigned)b) << 16);
}

// ---- K1: codebook = emb @ proj^T -> cb[k][d] fp32, eh/el bf16 [k][d] ----
__global__ __launch_bounds__(256)
void k_codebook(const float* __restrict__ emb, const float* __restrict__ proj,
                float* __restrict__ cb, u16* __restrict__ eh, u16* __restrict__ el) {
  __shared__ float et[64 * 65];
  __shared__ float pt[64 * 65];
  const int t = threadIdx.x;
  const int tx = t & 15, ty = t >> 4;
  const int kb = blockIdx.x * 64;
  const int db = blockIdx.y * 64;
  float acc[4][4];
#pragma unroll
  for (int u = 0; u < 4; ++u)
#pragma unroll
    for (int v = 0; v < 4; ++v) acc[u][v] = 0.f;

  const int jm = t & 15;
  const int q  = t >> 4;

  for (int jc = 0; jc < Dd; jc += 64) {
    __syncthreads();
#pragma unroll
    for (int i = 0; i < 4; ++i) {
      const int row = q + i * 16;
      const float4 e4 = *(const float4*)(emb  + (size_t)(kb + row) * Dd + jc + jm * 4);
      const float4 p4 = *(const float4*)(proj + (size_t)(db + row) * Dd + jc + jm * 4);
      et[(jm*4 + 0) * 65 + row] = e4.x;
      et[(jm*4 + 1) * 65 + row] = e4.y;
      et[(jm*4 + 2) * 65 + row] = e4.z;
      et[(jm*4 + 3) * 65 + row] = e4.w;
      pt[(jm*4 + 0) * 65 + row] = p4.x;
      pt[(jm*4 + 1) * 65 + row] = p4.y;
      pt[(jm*4 + 2) * 65 + row] = p4.z;
      pt[(jm*4 + 3) * 65 + row] = p4.w;
    }
    __syncthreads();
#pragma unroll 16
    for (int j = 0; j < 64; ++j) {
      float a[4], b[4];
#pragma unroll
      for (int u = 0; u < 4; ++u) a[u] = et[j*65 + ty*4 + u];
#pragma unroll
      for (int v = 0; v < 4; ++v) b[v] = pt[j*65 + tx*4 + v];
#pragma unroll
      for (int u = 0; u < 4; ++u)
#pragma unroll
        for (int v = 0; v < 4; ++v) acc[u][v] = fmaf(a[u], b[v], acc[u][v]);
    }
  }
#pragma unroll
  for (int u = 0; u < 4; ++u) {
    const int k = kb + ty*4 + u;
#pragma unroll
    for (int v = 0; v < 4; ++v) {
      const int d = db + tx*4 + v;
      const float val = acc[u][v];
      cb[(size_t)k * Dd + d] = val;
      const u16 hb = f2bf(val);
      eh[(size_t)k * Dd + d] = hb;
      el[(size_t)k * Dd + d] = f2bf(val - bf2f(hb));
    }
  }
}

// ---- K1b: per-code norms from cb rows (same ascending-d fmaf chain bits) ----
__global__ __launch_bounds__(256)
void k_norms(const float* __restrict__ cb, float* __restrict__ norms) {
  const int k = blockIdx.x * 256 + threadIdx.x;
  const float* row = cb + (size_t)k * Dd;
  float s = 0.f;
  for (int d = 0; d < Dd; d += 4) {
    const float4 v = *(const float4*)(row + d);
    s = fmaf(v.x, v.x, s);
    s = fmaf(v.y, v.y, s);
    s = fmaf(v.z, v.z, s);
    s = fmaf(v.w, v.w, s);
  }
  norms[k] = s;
}

// ---- K1c: transpose z -> zh/zl bf16 [n][d], znorm (ascending-d chain) ----
__global__ __launch_bounds__(256)
void k_prep_z(const float* __restrict__ z, u16* __restrict__ zh,
              u16* __restrict__ zl, float* __restrict__ znorm) {
  __shared__ float tile[256 * 33];
  const int t = threadIdx.x;
  const int blk = blockIdx.x;            // b*32 + h
  const int w = t & 31, rg = t >> 5;
  const size_t zbase = (size_t)(blk >> 5) * 262144 + (size_t)(blk & 31) * 32 + w;
#pragma unroll 8
  for (int i = 0; i < 32; ++i) {
    const int d = rg * 32 + i;
    tile[d * 33 + w] = z[zbase + (size_t)d * 1024];
  }
  __syncthreads();
  if (t < 32) {
    float s = 0.f;
    for (int d = 0; d < Dd; ++d) {
      const float v = tile[d * 33 + t];
      s = fmaf(v, v, s);
    }
    znorm[blk * 32 + t] = s;
  }
  const int nl = t >> 3, seg = t & 7;
  const size_t obase = (size_t)(blk * 32 + nl) * Dd + seg * 32;
#pragma unroll
  for (int j = 0; j < 4; ++j) {
    u16 hb[8], lb[8];
#pragma unroll
    for (int e = 0; e < 8; ++e) {
      const float v = tile[(seg * 32 + j * 8 + e) * 33 + nl];
      hb[e] = f2bf(v);
      lb[e] = f2bf(v - bf2f(hb[e]));
    }
    *(uint4*)(zh + obase + j * 8) = *(const uint4*)hb;
    *(uint4*)(zl + obase + j * 8) = *(const uint4*)lb;
  }
}

// ---- K2a: MFMA filter pass. Block 128 rows x 1024 cols (8 kt of 128) ----
// Wave tile 64x64 per kt; A/B fragment layouts as R6 (HW-verified mappings).
__global__ __launch_bounds__(256, 3)
void k_pass1(const u16* __restrict__ zh, const u16* __restrict__ zl,
             const u16* __restrict__ eh, const u16* __restrict__ el,
             const float* __restrict__ norms, const float* __restrict__ znorm,
             unsigned* __restrict__ list, unsigned* __restrict__ counter) {
  __shared__ unsigned runmin[128];       // per-row monof(min score) within block
  const int t    = threadIdx.x;
  const int lane = t & 63;
  const int wv   = t >> 6;
  const int ml   = lane & 15;
  const int qd   = lane >> 4;
  const int nblk = blockIdx.y * 128;
  const int kblk = blockIdx.x * 1024;
  const int nbase = nblk + (wv >> 1) * 64;

  for (int i = t; i < 128; i += 256) runmin[i] = 0xFFFFFFFFu;
  __syncthreads();

  float zn[4][4];
#pragma unroll
  for (int rt = 0; rt < 4; ++rt)
#pragma unroll
    for (int r = 0; r < 4; ++r)
      zn[rt][r] = znorm[nbase + rt * 16 + qd * 4 + r];

#pragma unroll 1
  for (int kt = 0; kt < 8; ++kt) {
    const int kbase = kblk + kt * 128 + (wv & 1) * 64;
    f32x4 acc[4][4];
#pragma unroll
    for (int rt = 0; rt < 4; ++rt)
#pragma unroll
      for (int ct = 0; ct < 4; ++ct) acc[rt][ct] = (f32x4)0.f;

#pragma unroll 1
    for (int dc = 0; dc < Dd; dc += 32) {
      short8 Ah[4], Al[4];
#pragma unroll
      for (int rt = 0; rt < 4; ++rt) {
        const size_t off = (size_t)(nbase + rt * 16 + ml) * Dd + dc + qd * 8;
        Ah[rt] = *(const short8*)(zh + off);
        Al[rt] = *(const short8*)(zl + off);
      }
#pragma unroll
      for (int ct = 0; ct < 4; ++ct) {
        const size_t off = (size_t)(kbase + ct * 16 + ml) * Dd + dc + qd * 8;
        const short8 Bh = *(const short8*)(eh + off);
        const short8 Bl = *(const short8*)(el + off);
#pragma unroll
        for (int rt = 0; rt < 4; ++rt) {
          acc[rt][ct] = __builtin_amdgcn_mfma_f32_16x16x32_bf16(Ah[rt], Bh, acc[rt][ct], 0, 0, 0);
          acc[rt][ct] = __builtin_amdgcn_mfma_f32_16x16x32_bf16(Ah[rt], Bl, acc[rt][ct], 0, 0, 0);
          acc[rt][ct] = __builtin_amdgcn_mfma_f32_16x16x32_bf16(Al[rt], Bh, acc[rt][ct], 0, 0, 0);
          acc[rt][ct] = __builtin_amdgcn_mfma_f32_16x16x32_bf16(Al[rt], Bl, acc[rt][ct], 0, 0, 0);
        }
      }
    }

    // approx scores; D layout col=kbase+ct*16+ml, row=nbase+rt*16+qd*4+r
    float scv[4][4][4];
#pragma unroll
    for (int ct = 0; ct < 4; ++ct) {
      const float nk = norms[kbase + ct * 16 + ml];
#pragma unroll
      for (int rt = 0; rt < 4; ++rt)
#pragma unroll
        for (int r = 0; r < 4; ++r)
          scv[rt][ct][r] = (zn[rt][r] + nk) - 2.0f * acc[rt][ct][r];
    }

    // update block-shared per-row running min
#pragma unroll
    for (int rt = 0; rt < 4; ++rt)
#pragma unroll
      for (int r = 0; r < 4; ++r) {
        float m = scv[rt][0][r];
#pragma unroll
        for (int ct = 1; ct < 4; ++ct) m = fminf(m, scv[rt][ct][r]);
#pragma unroll
        for (int s = 1; s < 16; s <<= 1) m = fminf(m, __shfl_xor(m, s, 64));
        if (ml == 0)
          atomicMin(&runmin[(wv >> 1) * 64 + rt * 16 + qd * 4 + r], monof(m));
      }
    __syncthreads();

    // append candidates within DLT of running min (wave-aggregated)
    float thr[4][4];
#pragma unroll
    for (int rt = 0; rt < 4; ++rt)
#pragma unroll
      for (int r = 0; r < 4; ++r)
        thr[rt][r] = unmonof(runmin[(wv >> 1) * 64 + rt * 16 + qd * 4 + r]) + DLT;

    unsigned cnt = 0;
#pragma unroll
    for (int rt = 0; rt < 4; ++rt)
#pragma unroll
      for (int ct = 0; ct < 4; ++ct)
#pragma unroll
        for (int r = 0; r < 4; ++r)
          cnt += (scv[rt][ct][r] <= thr[rt][r]) ? 1u : 0u;

    unsigned incl = cnt;
#pragma unroll
    for (int s = 1; s < 64; s <<= 1) {
      const unsigned o = __shfl_up(incl, s, 64);
      if (lane >= s) incl += o;
    }
    const unsigned total = __shfl(incl, 63, 64);
    unsigned base = 0;
    if (lane == 63 && total > 0) base = atomicAdd(counter, total);
    base = __shfl(base, 63, 64);
    if (total > 0 && cnt > 0) {
      unsigned w = base + incl - cnt;
#pragma unroll
      for (int rt = 0; rt < 4; ++rt)
#pragma unroll
        for (int ct = 0; ct < 4; ++ct)
#pragma unroll
          for (int r = 0; r < 4; ++r)
            if (scv[rt][ct][r] <= thr[rt][r]) {
              if (w < CAP) {
                const unsigned n = (unsigned)(nbase + rt * 16 + qd * 4 + r);
                const unsigned k = (unsigned)(kbase + ct * 16 + ml);
                list[w] = (n << 13) | k;
              }
              ++w;
            }
    }
  }
}

// ---- K2b: exact rescore of survivors (bit-identical chain to R2-R5) ----
__global__ __launch_bounds__(256)
void k_rescore(const float* __restrict__ z, const float* __restrict__ cb,
               const float* __restrict__ norms, const float* __restrict__ znorm,
               const unsigned* __restrict__ list, const unsigned* __restrict__ counter,
               unsigned long long* __restrict__ packed) {
  const unsigned i = blockIdx.x * 256 + threadIdx.x;
  const unsigned cnt = min(*counter, CAP);
  if (i >= cnt) return;
  const unsigned e = list[i];
  const int n = (int)(e >> 13);
  const int k = (int)(e & 8191u);
  const float* zp = z + (size_t)(n >> 10) * 262144 + (n & 1023);
  const float* cp = cb + (size_t)k * Dd;
  float acc = 0.f;
  for (int d = 0; d < Dd; d += 4) {
    const float4 c4 = *(const float4*)(cp + d);
    acc = fmaf(zp[(size_t)(d + 0) * 1024], c4.x, acc);
    acc = fmaf(zp[(size_t)(d + 1) * 1024], c4.y, acc);
    acc = fmaf(zp[(size_t)(d + 2) * 1024], c4.z, acc);
    acc = fmaf(zp[(size_t)(d + 3) * 1024], c4.w, acc);
  }
  const float sc = (znorm[n] + norms[k]) - 2.0f * acc;
  atomicMin(&packed[n], ((unsigned long long)monof(sc) << 32) | (unsigned)k);
}

// ---- K3: gather codes, write out (NCHW), idx floats, reduce SSE ----
__global__ __launch_bounds__(256)
void k_output(const float* __restrict__ z, const float* __restrict__ cb,
              const unsigned long long* __restrict__ packed,
              float* __restrict__ out, float* __restrict__ idxf,
              float* __restrict__ ssum) {
  __shared__ float zqT[256 * 33];
  __shared__ float part[4];
  const int t = threadIdx.x;
  const int blk = blockIdx.x;       // = b*32 + h
  const int nbase = blk * 32;

  {
    const int nl = t >> 3, m = t & 7;
    const int idx = (int)(packed[nbase + nl] & 0xFFFFFFFFull);
    const float* row = cb + (size_t)idx * Dd;
#pragma unroll
    for (int i = 0; i < 8; ++i) {
      const int d0 = m * 4 + i * 32;
      const float4 v = *(const float4*)(row + d0);
      zqT[(d0 + 0) * 33 + nl] = v.x;
      zqT[(d0 + 1) * 33 + nl] = v.y;
      zqT[(d0 + 2) * 33 + nl] = v.z;
      zqT[(d0 + 3) * 33 + nl] = v.w;
    }
    if (t < 32)
      idxf[nbase + t] = (float)(unsigned)(packed[nbase + t] & 0xFFFFFFFFull);
  }
  __syncthreads();

  const int w = t & 31, cg = t >> 5;
  const size_t base = (size_t)(blk >> 5) * 262144 + (size_t)(blk & 31) * 32 + w;
  float local = 0.f;
#pragma unroll
  for (int cc = 0; cc < 32; ++cc) {
    const int c = cg * 32 + cc;
    const float q  = zqT[c * 33 + w];
    const float zv = z[base + (size_t)c * 1024];
    out[base + (size_t)c * 1024] = q;
    const float dd = q - zv;
    local = fmaf(dd, dd, local);
  }
  float v = local;
#pragma unroll
  for (int m = 1; m < 64; m <<= 1) v += __shfl_xor(v, m, 64);
  if ((t & 63) == 0) part[t >> 6] = v;
  __syncthreads();
  if (t == 0) atomicAdd(ssum, part[0] + part[1] + part[2] + part[3]);
}

// ---- K4: finalize scalars ----
__global__ void k_final(const float* __restrict__ ssum, float* __restrict__ scal) {
  const float m = *ssum * INV_M;
  scal[0] = 1.25f * m;   // loss
  scal[1] = 0.25f * m;   // commitment_loss
  scal[2] = m;           // codebook_loss
}

extern "C" void kernel_launch(void* const* d_in, const int* in_sizes, int n_in,
                              void* d_out, int out_size, void* d_ws, size_t ws_size,
                              hipStream_t stream) {
  const float* z    = (const float*)d_in[0];
  const float* emb  = (const float*)d_in[1];
  const float* proj = (const float*)d_in[2];

  float* out  = (float*)d_out;
  float* scal = out + 4194304;
  float* idxf = out + 4194307;

  // ws: cb | norms | packed | znorm | zh zl eh el | list | counter | ssum  (~41.5 MB)
  float* cb    = (float*)d_ws;                          // 8 MB
  float* norms = cb + 2097152;                          // 32 KB
  unsigned long long* packed =
      (unsigned long long*)(norms + 8192);              // 128 KB
  float* znorm = (float*)(packed + 16384);              // 64 KB
  u16* zh = (u16*)(znorm + 16384);                      // 8.4 MB
  u16* zl = zh + 4194304;                               // 8.4 MB
  u16* eh = zl + 4194304;                               // 4.2 MB
  u16* el = eh + 2097152;                               // 4.2 MB
  unsigned* list    = (unsigned*)(el + 2097152);        // 8 MB
  unsigned* counter = list + CAP;                       // 4 B
  float* ssum = (float*)(counter + 1);                  // 4 B

  hipMemsetAsync(packed, 0xFF, 16384 * sizeof(unsigned long long), stream);
  hipMemsetAsync(counter, 0, sizeof(unsigned), stream);
  hipMemsetAsync(ssum, 0, sizeof(float), stream);

  k_codebook<<<dim3(128, 4), 256, 0, stream>>>(emb, proj, cb, eh, el);
  k_norms   <<<32, 256, 0, stream>>>(cb, norms);
  k_prep_z  <<<512, 256, 0, stream>>>(z, zh, zl, znorm);
  k_pass1   <<<dim3(8, 128), 256, 0, stream>>>(zh, zl, eh, el, norms, znorm, list, counter);
  k_rescore <<<CAP / 256, 256, 0, stream>>>(z, cb, norms, znorm, list, counter, packed);
  k_output  <<<512, 256, 0, stream>>>(z, cb, packed, out, idxf, ssum);
  k_final   <<<1, 1, 0, stream>>>(ssum, scal);

  (void)in_sizes; (void)n_in; (void)out_size; (void)ws_size;
}

// Round 8
// 400.178 us; speedup vs baseline: 2.5295x; 2.5295x over previous
//
#include <hip/hip_runtime.h>
#include <cfloat>

// VQ forward, MI355X. z[16,256,32,32] f32, emb[8192,256] f32, proj[256,256] f32.
// N = 16384 rows, K = 8192 codes, D = 256.
// d_out (floats): out[4194304] | loss | commitment | codebook_loss | idx_as_float[16384]
//
// R8 three-phase argmin:
//  scanA (bf16 MFMA, LDS-staged): per-row global approx-min (atomicMin u32 monof).
//  k_thresh: thr[n] = min + DLT, DLT=1e-3 >> worst-case score error 3.2e-4
//            (|err| <= 2*2^-8*sum|z_i e_i|, deterministic bound) -> winner always kept.
//  scanC (same computation, bit-identical): emit k with sc <= thr[n] into per-row
//            slots (~4.5/row mean; cap 32, overflow P~1e-18).
//  k_rescore: exact fp32 rescore of slots (deterministic blocked dot, ~1e-9 error,
//            same class as the chain that passed R2-R5); quantized fold
//            fl(fl(zn+nk)-2*dot); packed (monof<<32|k) min -> np first-index ties.

constexpr int Dd = 256;
constexpr float INV_M = 1.0f / 4194304.0f;
constexpr float DLT = 1e-3f;

typedef unsigned short u16;
typedef unsigned int u32;
typedef __attribute__((ext_vector_type(8))) short short8;   // 8 bf16
typedef __attribute__((ext_vector_type(4))) float f32x4;

#define GLOBAL_AS __attribute__((address_space(1)))
#define LDS_AS    __attribute__((address_space(3)))

__device__ __forceinline__ unsigned monof(float f) {
  unsigned u = __float_as_uint(f);
  return (u & 0x80000000u) ? ~u : (u | 0x80000000u);
}
__device__ __forceinline__ float unmonof(unsigned p) {
  unsigned u = (p & 0x80000000u) ? (p & 0x7FFFFFFFu) : ~p;
  return __uint_as_float(u);
}
__device__ __forceinline__ u16 f2bf(float x) {   // RNE float->bf16 bits
  unsigned u = __float_as_uint(x);
  u += 0x7FFFu + ((u >> 16) & 1u);
  return (u16)(u >> 16);
}

// ---- K1: codebook = emb @ proj^T -> cb[k][d] fp32 + eh bf16[k][d] ----
__global__ __launch_bounds__(256)
void k_codebook(const float* __restrict__ emb, const float* __restrict__ proj,
                float* __restrict__ cb, u16* __restrict__ eh) {
  __shared__ float et[64 * 65];
  __shared__ float pt[64 * 65];
  const int t = threadIdx.x;
  const int tx = t & 15, ty = t >> 4;
  const int kb = blockIdx.x * 64;
  const int db = blockIdx.y * 64;
  float acc[4][4];
#pragma unroll
  for (int u = 0; u < 4; ++u)
#pragma unroll
    for (int v = 0; v < 4; ++v) acc[u][v] = 0.f;

  const int jm = t & 15;
  const int q  = t >> 4;

  for (int jc = 0; jc < Dd; jc += 64) {
    __syncthreads();
#pragma unroll
    for (int i = 0; i < 4; ++i) {
      const int row = q + i * 16;
      const float4 e4 = *(const float4*)(emb  + (size_t)(kb + row) * Dd + jc + jm * 4);
      const float4 p4 = *(const float4*)(proj + (size_t)(db + row) * Dd + jc + jm * 4);
      et[(jm*4 + 0) * 65 + row] = e4.x;
      et[(jm*4 + 1) * 65 + row] = e4.y;
      et[(jm*4 + 2) * 65 + row] = e4.z;
      et[(jm*4 + 3) * 65 + row] = e4.w;
      pt[(jm*4 + 0) * 65 + row] = p4.x;
      pt[(jm*4 + 1) * 65 + row] = p4.y;
      pt[(jm*4 + 2) * 65 + row] = p4.z;
      pt[(jm*4 + 3) * 65 + row] = p4.w;
    }
    __syncthreads();
#pragma unroll 16
    for (int j = 0; j < 64; ++j) {
      float a[4], b[4];
#pragma unroll
      for (int u = 0; u < 4; ++u) a[u] = et[j*65 + ty*4 + u];
#pragma unroll
      for (int v = 0; v < 4; ++v) b[v] = pt[j*65 + tx*4 + v];
#pragma unroll
      for (int u = 0; u < 4; ++u)
#pragma unroll
        for (int v = 0; v < 4; ++v) acc[u][v] = fmaf(a[u], b[v], acc[u][v]);
    }
  }
#pragma unroll
  for (int u = 0; u < 4; ++u) {
    const int k = kb + ty*4 + u;
#pragma unroll
    for (int v = 0; v < 4; ++v) {
      const int d = db + tx*4 + v;
      const float val = acc[u][v];
      cb[(size_t)k * Dd + d] = val;
      eh[(size_t)k * Dd + d] = f2bf(val);
    }
  }
}

// ---- K1b: per-code norms (ascending-d fmaf chain) ----
__global__ __launch_bounds__(256)
void k_norms(const float* __restrict__ cb, float* __restrict__ norms) {
  const int k = blockIdx.x * 256 + threadIdx.x;
  const float* row = cb + (size_t)k * Dd;
  float s = 0.f;
  for (int d = 0; d < Dd; d += 4) {
    const float4 v = *(const float4*)(row + d);
    s = fmaf(v.x, v.x, s);
    s = fmaf(v.y, v.y, s);
    s = fmaf(v.z, v.z, s);
    s = fmaf(v.w, v.w, s);
  }
  norms[k] = s;
}

// ---- K1c: transpose z -> zh bf16 [n][d] + znorm ----
__global__ __launch_bounds__(256)
void k_prep_z(const float* __restrict__ z, u16* __restrict__ zh,
              float* __restrict__ znorm) {
  __shared__ float tile[256 * 33];
  const int t = threadIdx.x;
  const int blk = blockIdx.x;            // b*32 + h
  const int w = t & 31, rg = t >> 5;
  const size_t zbase = (size_t)(blk >> 5) * 262144 + (size_t)(blk & 31) * 32 + w;
#pragma unroll 8
  for (int i = 0; i < 32; ++i) {
    const int d = rg * 32 + i;
    tile[d * 33 + w] = z[zbase + (size_t)d * 1024];
  }
  __syncthreads();
  if (t < 32) {
    float s = 0.f;
    for (int d = 0; d < Dd; ++d) {
      const float v = tile[d * 33 + t];
      s = fmaf(v, v, s);
    }
    znorm[blk * 32 + t] = s;
  }
  const int nl = t >> 3, seg = t & 7;
  const size_t obase = (size_t)(blk * 32 + nl) * Dd + seg * 32;
#pragma unroll
  for (int j = 0; j < 4; ++j) {
    u16 hb[8];
#pragma unroll
    for (int e = 0; e < 8; ++e)
      hb[e] = f2bf(tile[(seg * 32 + j * 8 + e) * 33 + nl]);
    *(uint4*)(zh + obase + j * 8) = *(const uint4*)hb;
  }
}

// ---- K2: MFMA scan. Block 64 rows x 1024 cols; kt=4 x 256 cols; dh=4 x 64 d ----
// zs: 64 rows x 32 chunks (16B), slot = c ^ ((row&7)<<2)  -> 32 KB, staged once.
// es: 256 cols x 8 chunks, slot = c ^ (col&7)             -> 32 KB, per (kt,dh).
// Swizzle => every quarter-wave b128 read is 2-way max (free).  Wave tile 32x128.
template <bool EMIT>
__global__ __launch_bounds__(256, 2)
void k_scan(const u16* __restrict__ zh, const u16* __restrict__ eh,
            const float* __restrict__ norms, const float* __restrict__ znorm,
            u32* __restrict__ rowminG, const float* __restrict__ rowThr,
            u32* __restrict__ rowcnt, u16* __restrict__ slots) {
  __shared__ u16 zs[64 * 256];   // 32 KB
  __shared__ u16 es[256 * 64];   // 32 KB  [col][slot0..7][8 shorts]
  const int t    = threadIdx.x;
  const int lane = t & 63;
  const int ml   = lane & 15;
  const int qd   = lane >> 4;
  const int wvu  = __builtin_amdgcn_readfirstlane(t >> 6);
  const int rowhalf = wvu & 1;           // 0/1 -> 32 rows
  const int colhalf = wvu >> 1;          // 0/1 -> 128 cols (of kt's 256)
  const int bid  = blockIdx.x;
  const int kb   = (bid & 7) * 1024;     // colgroup -> XCD-local eh reuse
  const int nb   = (bid >> 3) * 64;

  // ---- stage zs once: wave wvu covers rows [wvu*16, +16) ----
#pragma unroll
  for (int i = 0; i < 8; ++i) {
    const int r0 = wvu * 16 + i * 2;
    const int row_l = r0 + (lane >> 5);
    const int c = (lane & 31) ^ ((row_l & 7) << 2);
    const u16* gp = zh + (size_t)(nb + row_l) * 256 + c * 8;
    __builtin_amdgcn_global_load_lds((const GLOBAL_AS void*)gp,
                                     (LDS_AS void*)(zs + r0 * 256), 16, 0, 0);
  }

  // per-thread rows: n = nb + rowhalf*32 + rt*16 + qd*4 + r
  float zn[2][4], thr[2][4];
#pragma unroll
  for (int rt = 0; rt < 2; ++rt) {
    const int nr = nb + rowhalf * 32 + rt * 16 + qd * 4;
    const f32x4 z4 = *(const f32x4*)(znorm + nr);
#pragma unroll
    for (int r = 0; r < 4; ++r) zn[rt][r] = z4[r];
    if (EMIT) {
      const f32x4 t4 = *(const f32x4*)(rowThr + nr);
#pragma unroll
      for (int r = 0; r < 4; ++r) thr[rt][r] = t4[r];
    }
  }

  float mv[2][4];
#pragma unroll
  for (int rt = 0; rt < 2; ++rt)
#pragma unroll
    for (int r = 0; r < 4; ++r) mv[rt][r] = FLT_MAX;

#pragma unroll 1
  for (int kt = 0; kt < 4; ++kt) {
    f32x4 acc[2][8];
#pragma unroll
    for (int rt = 0; rt < 2; ++rt)
#pragma unroll
      for (int ct = 0; ct < 8; ++ct) acc[rt][ct] = (f32x4)0.f;

#pragma unroll 1
    for (int dh = 0; dh < 4; ++dh) {
      __syncthreads();   // protect es from previous sub-tile readers
      // stage es: wave wvu covers cols [wvu*64, +64), 8 cols per instr
#pragma unroll
      for (int i = 0; i < 8; ++i) {
        const int colbase = wvu * 64 + i * 8;
        const int col_l = colbase + (lane >> 3);
        const int c = (lane & 7) ^ (col_l & 7);
        const u16* gp = eh + (size_t)(kb + kt * 256 + col_l) * 256 + dh * 64 + c * 8;
        __builtin_amdgcn_global_load_lds((const GLOBAL_AS void*)gp,
                                         (LDS_AS void*)(es + colbase * 64), 16, 0, 0);
      }
      __syncthreads();   // staging (incl. zs on dh==0,kt==0) complete

#pragma unroll
      for (int dc2 = 0; dc2 < 2; ++dc2) {
        short8 Af[2], Bf[8];
#pragma unroll
        for (int rt = 0; rt < 2; ++rt) {
          const int row_l = rowhalf * 32 + rt * 16 + ml;
          const int cg = dh * 8 + dc2 * 4 + qd;
          const int slot = cg ^ ((row_l & 7) << 2);
          Af[rt] = *(const short8*)(zs + row_l * 256 + slot * 8);
        }
#pragma unroll
        for (int ct = 0; ct < 8; ++ct) {
          const int col_l = colhalf * 128 + ct * 16 + ml;
          const int c = dc2 * 4 + qd;
          const int slot = c ^ (col_l & 7);
          Bf[ct] = *(const short8*)(es + col_l * 64 + slot * 8);
        }
#pragma unroll
        for (int rt = 0; rt < 2; ++rt)
#pragma unroll
          for (int ct = 0; ct < 8; ++ct)
            acc[rt][ct] = __builtin_amdgcn_mfma_f32_16x16x32_bf16(
                Af[rt], Bf[ct], acc[rt][ct], 0, 0, 0);
      }
    }

    // fold this kt's 128 cols (per thread: 8 cols via ct, rows via rt,r)
#pragma unroll
    for (int ct = 0; ct < 8; ++ct) {
      const int k = kb + kt * 256 + colhalf * 128 + ct * 16 + ml;
      const float nk = norms[k];
#pragma unroll
      for (int rt = 0; rt < 2; ++rt)
#pragma unroll
        for (int r = 0; r < 4; ++r) {
          const float sc = (zn[rt][r] + nk) - 2.0f * acc[rt][ct][r];
          if (!EMIT) {
            mv[rt][r] = fminf(mv[rt][r], sc);
          } else if (sc <= thr[rt][r]) {
            const int n = nb + rowhalf * 32 + rt * 16 + qd * 4 + r;
            const u32 pos = atomicAdd(&rowcnt[n], 1u);
            if (pos < 32u) slots[n * 32 + pos] = (u16)k;
          }
        }
    }
  }

  if (!EMIT) {
#pragma unroll
    for (int rt = 0; rt < 2; ++rt)
#pragma unroll
      for (int r = 0; r < 4; ++r) {
        float m = mv[rt][r];
#pragma unroll
        for (int s = 1; s < 16; s <<= 1) m = fminf(m, __shfl_xor(m, s, 64));
        if (ml == 0)
          atomicMin(&rowminG[nb + rowhalf * 32 + rt * 16 + qd * 4 + r], monof(m));
      }
  }
}

// ---- K2b: threshold ----
__global__ __launch_bounds__(256)
void k_thresh(const u32* __restrict__ rowminG, float* __restrict__ rowThr) {
  const int n = blockIdx.x * 256 + threadIdx.x;
  rowThr[n] = unmonof(rowminG[n]) + DLT;
}

// ---- K2c: exact rescore of slot candidates ----
// Block per (b,h): 32 rows; LDS z-tile [32][261] fp32; wave per 4 rows.
__global__ __launch_bounds__(256)
void k_rescore(const float* __restrict__ z, const float* __restrict__ cb,
               const float* __restrict__ norms, const float* __restrict__ znorm,
               const u32* __restrict__ rowcnt, const u16* __restrict__ slots,
               unsigned long long* __restrict__ packed) {
  __shared__ float ztl[32 * 261];
  const int t = threadIdx.x;
  const int blk = blockIdx.x;          // b*32 + h
  const int w = t & 31, dg = t >> 5;
  const size_t zbase = (size_t)(blk >> 5) * 262144 + (size_t)(blk & 31) * 32;
#pragma unroll 8
  for (int i = 0; i < 32; ++i) {
    const int d = dg * 32 + i;
    ztl[w * 261 + d] = z[zbase + (size_t)d * 1024 + w];
  }
  __syncthreads();

  const int lane = t & 63;
  const int wv = t >> 6;               // 4 waves? no: 256 thr = 4 waves
  // 4 waves x 8 rows each
#pragma unroll 1
  for (int i = 0; i < 8; ++i) {
    const int rl = wv * 8 + i;
    const int n = blk * 32 + rl;
    const u32 cnt = min(rowcnt[n], 32u);
    const float znr = znorm[n];
    unsigned long long best = 0xFFFFFFFFFFFFFFFFull;
    for (u32 c = 0; c < cnt; ++c) {
      const int k = (int)slots[n * 32 + c];
      const float4 c4 = *(const float4*)(cb + (size_t)k * Dd + lane * 4);
      const float* zp = ztl + rl * 261 + lane * 4;
      float p = 0.f;
      p = fmaf(zp[0], c4.x, p);
      p = fmaf(zp[1], c4.y, p);
      p = fmaf(zp[2], c4.z, p);
      p = fmaf(zp[3], c4.w, p);
#pragma unroll
      for (int s = 1; s < 64; s <<= 1) p += __shfl_xor(p, s, 64);
      const float sc = (znr + norms[k]) - 2.0f * p;   // quantized fold
      const unsigned long long pk =
          ((unsigned long long)monof(sc) << 32) | (unsigned)k;
      if (pk < best) best = pk;                        // lexicographic: ties -> min k
    }
    if (lane == 0 && cnt > 0) packed[n] = best;
  }
}

// ---- K3: gather codes, write out (NCHW), idx floats, reduce SSE ----
__global__ __launch_bounds__(256)
void k_output(const float* __restrict__ z, const float* __restrict__ cb,
              const unsigned long long* __restrict__ packed,
              float* __restrict__ out, float* __restrict__ idxf,
              float* __restrict__ ssum) {
  __shared__ float zqT[256 * 33];
  __shared__ float part[4];
  const int t = threadIdx.x;
  const int blk = blockIdx.x;       // = b*32 + h
  const int nbase = blk * 32;

  {
    const int nl = t >> 3, m = t & 7;
    const int idx = (int)(packed[nbase + nl] & 0xFFFFFFFFull);
    const float* row = cb + (size_t)idx * Dd;
#pragma unroll
    for (int i = 0; i < 8; ++i) {
      const int d0 = m * 4 + i * 32;
      const float4 v = *(const float4*)(row + d0);
      zqT[(d0 + 0) * 33 + nl] = v.x;
      zqT[(d0 + 1) * 33 + nl] = v.y;
      zqT[(d0 + 2) * 33 + nl] = v.z;
      zqT[(d0 + 3) * 33 + nl] = v.w;
    }
    if (t < 32)
      idxf[nbase + t] = (float)(unsigned)(packed[nbase + t] & 0xFFFFFFFFull);
  }
  __syncthreads();

  const int w = t & 31, cg = t >> 5;
  const size_t base = (size_t)(blk >> 5) * 262144 + (size_t)(blk & 31) * 32 + w;
  float local = 0.f;
#pragma unroll
  for (int cc = 0; cc < 32; ++cc) {
    const int c = cg * 32 + cc;
    const float q  = zqT[c * 33 + w];
    const float zv = z[base + (size_t)c * 1024];
    out[base + (size_t)c * 1024] = q;
    const float dd = q - zv;
    local = fmaf(dd, dd, local);
  }
  float v = local;
#pragma unroll
  for (int m = 1; m < 64; m <<= 1) v += __shfl_xor(v, m, 64);
  if ((t & 63) == 0) part[t >> 6] = v;
  __syncthreads();
  if (t == 0) atomicAdd(ssum, part[0] + part[1] + part[2] + part[3]);
}

// ---- K4: finalize scalars ----
__global__ void k_final(const float* __restrict__ ssum, float* __restrict__ scal) {
  const float m = *ssum * INV_M;
  scal[0] = 1.25f * m;   // loss
  scal[1] = 0.25f * m;   // commitment_loss
  scal[2] = m;           // codebook_loss
}

extern "C" void kernel_launch(void* const* d_in, const int* in_sizes, int n_in,
                              void* d_out, int out_size, void* d_ws, size_t ws_size,
                              hipStream_t stream) {
  const float* z    = (const float*)d_in[0];
  const float* emb  = (const float*)d_in[1];
  const float* proj = (const float*)d_in[2];

  float* out  = (float*)d_out;
  float* scal = out + 4194304;
  float* idxf = out + 4194307;

  // ws (~22 MB): cb | norms | packed | znorm | zh | eh | rowminG | rowThr | rowcnt | slots | ssum
  float* cb    = (float*)d_ws;                          // 8 MB
  float* norms = cb + 2097152;                          // 32 KB
  unsigned long long* packed =
      (unsigned long long*)(norms + 8192);              // 128 KB
  float* znorm = (float*)(packed + 16384);              // 64 KB
  u16* zh = (u16*)(znorm + 16384);                      // 8.4 MB
  u16* eh = zh + 4194304;                               // 4.2 MB
  u32* rowminG = (u32*)(eh + 2097152);                  // 64 KB
  float* rowThr = (float*)(rowminG + 16384);            // 64 KB
  u32* rowcnt = (u32*)(rowThr + 16384);                 // 64 KB
  u16* slots = (u16*)(rowcnt + 16384);                  // 1 MB
  float* ssum = (float*)(slots + 16384 * 32);           // 4 B

  hipMemsetAsync(rowminG, 0xFF, 16384 * sizeof(u32), stream);
  hipMemsetAsync(rowcnt, 0, 16384 * sizeof(u32), stream);
  hipMemsetAsync(packed, 0xFF, 16384 * sizeof(unsigned long long), stream);
  hipMemsetAsync(ssum, 0, sizeof(float), stream);

  k_codebook<<<dim3(128, 4), 256, 0, stream>>>(emb, proj, cb, eh);
  k_norms   <<<32, 256, 0, stream>>>(cb, norms);
  k_prep_z  <<<512, 256, 0, stream>>>(z, zh, znorm);
  k_scan<false><<<2048, 256, 0, stream>>>(zh, eh, norms, znorm,
                                          rowminG, rowThr, rowcnt, slots);
  k_thresh  <<<64, 256, 0, stream>>>(rowminG, rowThr);
  k_scan<true> <<<2048, 256, 0, stream>>>(zh, eh, norms, znorm,
                                          rowminG, rowThr, rowcnt, slots);
  k_rescore <<<512, 256, 0, stream>>>(z, cb, norms, znorm, rowcnt, slots, packed);
  k_output  <<<512, 256, 0, stream>>>(z, cb, packed, out, idxf, ssum);
  k_final   <<<1, 1, 0, stream>>>(ssum, scal);

  (void)in_sizes; (void)n_in; (void)out_size; (void)ws_size;
}